// Round 1
// baseline (587.502 us; speedup 1.0000x reference)
//
#include <hip/hip_runtime.h>
#include <hip/hip_bf16.h>
#include <stdint.h>

// Problem constants
#define BATCH   4096
#define CONTENT 200
#define EMBED   128
#define HIDDEN  1024
#define KDIM    (CONTENT*EMBED)   // 25600
#define KSTEPS  (KDIM/32)         // 800 k-steps of 32
#define SPLITK  3
#define KCHUNK  267               // ceil(800/3); last chunk gets 266

typedef __bf16 bf16_t;
typedef __bf16 bf16x8 __attribute__((ext_vector_type(8)));
typedef float  f32x4  __attribute__((ext_vector_type(4)));

// Workspace layout (bytes)
#define WS_A     0ull                       // A bf16 [4096][25600]  = 209,715,200 B
#define WS_W1    209715200ull               // w1 bf16 [1024][25600] =  52,428,800 B
#define WS_HP    262144000ull               // 3 x f32 [4096][1024]  =  50,331,648 B
#define HP_STRIDE 4194304ull                // floats per partial buffer

__device__ __forceinline__ void gload_lds16(const void* g, void* l) {
  __builtin_amdgcn_global_load_lds(
      (const __attribute__((address_space(1))) uint32_t*)g,
      (__attribute__((address_space(3))) uint32_t*)l, 16, 0, 0);
}

// ---------------- Kernel 1: cast w1 f32 -> bf16 ----------------
__global__ __launch_bounds__(256) void k_cast_w1(const float* __restrict__ w1,
                                                 bf16_t* __restrict__ o) {
  const long long NU = (long long)HIDDEN * KDIM / 8;  // 3,276,800 units of 8
  long long stride = (long long)gridDim.x * 256;
  for (long long u = (long long)blockIdx.x * 256 + threadIdx.x; u < NU; u += stride) {
    const float4* s = (const float4*)(w1 + u * 8);
    float4 f0 = s[0], f1 = s[1];
    bf16x8 r;
    r[0]=(bf16_t)f0.x; r[1]=(bf16_t)f0.y; r[2]=(bf16_t)f0.z; r[3]=(bf16_t)f0.w;
    r[4]=(bf16_t)f1.x; r[5]=(bf16_t)f1.y; r[6]=(bf16_t)f1.z; r[7]=(bf16_t)f1.w;
    *(bf16x8*)(o + u * 8) = r;
  }
}

// ---------------- Kernel 2: gather + cast A = emb[x] ----------------
__global__ __launch_bounds__(256) void k_gather(const int* __restrict__ x,
                                                const float* __restrict__ emb,
                                                bf16_t* __restrict__ A) {
  const long long NU = (long long)BATCH * KDIM / 8;   // 13,107,200 units of 8
  long long stride = (long long)gridDim.x * 256;
  for (long long u = (long long)blockIdx.x * 256 + threadIdx.x; u < NU; u += stride) {
    int m  = (int)(u / 3200);    // 25600/8 units per batch row
    int r  = (int)(u % 3200);
    int c  = r >> 4;             // token position (16 units per 128-wide embedding)
    int ch = r & 15;             // 8-elem chunk within the embedding vector
    int idx = x[m * CONTENT + c];
    const float4* s = (const float4*)(emb + (size_t)idx * EMBED + ch * 8);
    float4 f0 = s[0], f1 = s[1];
    float sc = (idx == 0) ? 0.0f : 1.0f;   // padding_idx = 0
    bf16x8 o;
    o[0]=(bf16_t)(f0.x*sc); o[1]=(bf16_t)(f0.y*sc); o[2]=(bf16_t)(f0.z*sc); o[3]=(bf16_t)(f0.w*sc);
    o[4]=(bf16_t)(f1.x*sc); o[5]=(bf16_t)(f1.y*sc); o[6]=(bf16_t)(f1.z*sc); o[7]=(bf16_t)(f1.w*sc);
    *(bf16x8*)(A + u * 8) = o;
  }
}

// ---------------- Kernel 3: GEMM  h_part[z] = A[128-tile] @ W^T[128-tile] ----------------
// A: [4096][25600] bf16 (row-major, K-major), W: [1024][25600] bf16 (K-major).
// 128x128 tile, BK=32, 256 threads = 4 waves, each wave a 64x64 sub-tile
// of 4x4 mfma_f32_16x16x32_bf16 fragments. split-K over blockIdx.z.
__global__ __launch_bounds__(256) void k_gemm(const bf16_t* __restrict__ A,
                                              const bf16_t* __restrict__ W,
                                              float* __restrict__ hp) {
  __shared__ char smem[16384];          // A-tile 8KB | B-tile 8KB
  const int tid = threadIdx.x;
  const int w = tid >> 6, l = tid & 63;
  const int m0 = blockIdx.x * 128;
  const int n0 = blockIdx.y * 128;
  const int chunk = blockIdx.z;
  const int ks_begin = chunk * KCHUNK;
  int ks_end = ks_begin + KCHUNK; if (ks_end > KSTEPS) ks_end = KSTEPS;

  // --- staging addresses: tile is 8KB linear; each thread stages 16B x 2 rounds
  const int q1 = w * 1024 + l * 16;     // round-0 byte offset within tile
  const int q2 = q1 + 4096;             // round-1
  const char* Ab = (const char*)A;
  const char* Wb = (const char*)W;
  // row = q>>6 (64B = 32 bf16 per row), byte-in-row = q&63; K rowstride = 51200B
  const char* a0 = Ab + (size_t)(m0 + (q1 >> 6)) * 51200 + (q1 & 63) + (size_t)ks_begin * 64;
  const char* a1 = Ab + (size_t)(m0 + (q2 >> 6)) * 51200 + (q2 & 63) + (size_t)ks_begin * 64;
  const char* b0 = Wb + (size_t)(n0 + (q1 >> 6)) * 51200 + (q1 & 63) + (size_t)ks_begin * 64;
  const char* b1 = Wb + (size_t)(n0 + (q2 >> 6)) * 51200 + (q2 & 63) + (size_t)ks_begin * 64;
  char* ldsA0 = smem + w * 1024;        // wave-uniform base; HW adds lane*16
  char* ldsA1 = smem + 4096 + w * 1024;
  char* ldsB0 = smem + 8192 + w * 1024;
  char* ldsB1 = smem + 12288 + w * 1024;

  const int wr = w >> 1, wc = w & 1;    // wave's 64x64 sub-tile coords
  const int lane_r = l & 15;            // fragment row
  const int kb = (l >> 4) * 16;         // k-chunk byte offset (8 bf16)
  const char* AsB = smem;
  const char* BsB = smem + 8192;

  f32x4 acc[4][4];
  #pragma unroll
  for (int i = 0; i < 4; ++i)
    #pragma unroll
    for (int j = 0; j < 4; ++j)
      acc[i][j] = (f32x4){0.f, 0.f, 0.f, 0.f};

  for (int ks = ks_begin; ks < ks_end; ++ks) {
    gload_lds16(a0, ldsA0);
    gload_lds16(a1, ldsA1);
    gload_lds16(b0, ldsB0);
    gload_lds16(b1, ldsB1);
    a0 += 64; a1 += 64; b0 += 64; b1 += 64;
    __syncthreads();                    // compiler drains vmcnt(0) before barrier

    bf16x8 af[4], bfr[4];
    #pragma unroll
    for (int i = 0; i < 4; ++i) {
      af[i]  = *(const bf16x8*)(AsB + ((wr * 64 + i * 16 + lane_r) << 6) + kb);
      bfr[i] = *(const bf16x8*)(BsB + ((wc * 64 + i * 16 + lane_r) << 6) + kb);
    }
    #pragma unroll
    for (int i = 0; i < 4; ++i)
      #pragma unroll
      for (int j = 0; j < 4; ++j)
        acc[i][j] = __builtin_amdgcn_mfma_f32_16x16x32_bf16(af[i], bfr[j], acc[i][j], 0, 0, 0);
    __syncthreads();
  }

  // Epilogue: C/D layout col = lane&15, row = (lane>>4)*4 + reg  [m89-verified]
  float* hout = hp + (size_t)chunk * HP_STRIDE;
  const int colBase = n0 + wc * 64 + lane_r;
  const int rowBase = m0 + wr * 64 + (l >> 4) * 4;
  #pragma unroll
  for (int i = 0; i < 4; ++i)
    #pragma unroll
    for (int j = 0; j < 4; ++j)
      #pragma unroll
      for (int r = 0; r < 4; ++r)
        hout[(size_t)(rowBase + i * 16 + r) * HIDDEN + colBase + j * 16] = acc[i][j][r];
}

// ---------------- Kernel 4: sum partials + bias + relu + layer2 + softmax ----------------
__global__ __launch_bounds__(256) void k_final(const float* __restrict__ hp,
                                               const float* __restrict__ b1,
                                               const float* __restrict__ w2,
                                               const float* __restrict__ b2,
                                               float* __restrict__ out) {
  const int tid = threadIdx.x;
  const int w = tid >> 6, l = tid & 63;
  const int m = blockIdx.x * 4 + w;     // one wave per batch row
  const float* r0 = hp + (size_t)m * HIDDEN;
  const float* r1 = r0 + HP_STRIDE;
  const float* r2 = r1 + HP_STRIDE;
  float l0 = 0.f, l1 = 0.f;
  #pragma unroll
  for (int t = 0; t < 4; ++t) {
    int j = t * 256 + l * 4;            // lanes contiguous within each 1KB stripe
    float4 p0 = *(const float4*)(r0 + j);
    float4 p1 = *(const float4*)(r1 + j);
    float4 p2 = *(const float4*)(r2 + j);
    float4 bb = *(const float4*)(b1 + j);
    float4 wa = *(const float4*)(w2 + j);
    float4 wb = *(const float4*)(w2 + HIDDEN + j);
    float h;
    h = p0.x + p1.x + p2.x + bb.x; h = fmaxf(h, 0.f); l0 += h * wa.x; l1 += h * wb.x;
    h = p0.y + p1.y + p2.y + bb.y; h = fmaxf(h, 0.f); l0 += h * wa.y; l1 += h * wb.y;
    h = p0.z + p1.z + p2.z + bb.z; h = fmaxf(h, 0.f); l0 += h * wa.z; l1 += h * wb.z;
    h = p0.w + p1.w + p2.w + bb.w; h = fmaxf(h, 0.f); l0 += h * wa.w; l1 += h * wb.w;
  }
  #pragma unroll
  for (int off = 32; off > 0; off >>= 1) {
    l0 += __shfl_xor(l0, off, 64);
    l1 += __shfl_xor(l1, off, 64);
  }
  if (l == 0) {
    float z0 = l0 + b2[0], z1 = l1 + b2[1];
    float mx = fmaxf(z0, z1);
    float e0 = expf(z0 - mx), e1 = expf(z1 - mx);
    float s = 1.f / (e0 + e1);
    out[2 * m]     = e0 * s;
    out[2 * m + 1] = e1 * s;
  }
}

extern "C" void kernel_launch(void* const* d_in, const int* in_sizes, int n_in,
                              void* d_out, int out_size, void* d_ws, size_t ws_size,
                              hipStream_t stream) {
  (void)in_sizes; (void)n_in; (void)out_size; (void)ws_size;
  const int*   x   = (const int*)d_in[0];
  const float* emb = (const float*)d_in[1];
  const float* w1  = (const float*)d_in[2];
  const float* b1  = (const float*)d_in[3];
  const float* w2  = (const float*)d_in[4];
  const float* b2  = (const float*)d_in[5];
  float* out = (float*)d_out;
  char* ws = (char*)d_ws;
  bf16_t* Abf = (bf16_t*)(ws + WS_A);
  bf16_t* Wbf = (bf16_t*)(ws + WS_W1);
  float*  hp  = (float*)(ws + WS_HP);

  hipLaunchKernelGGL(k_cast_w1, dim3(2048), dim3(256), 0, stream, w1, Wbf);
  hipLaunchKernelGGL(k_gather,  dim3(2048), dim3(256), 0, stream, x, emb, Abf);
  hipLaunchKernelGGL(k_gemm,    dim3(BATCH/128, HIDDEN/128, SPLITK), dim3(256), 0, stream,
                     Abf, Wbf, hp);
  hipLaunchKernelGGL(k_final,   dim3(BATCH/4), dim3(256), 0, stream, hp, b1, w2, b2, out);
}

// Round 2
// 421.236 us; speedup vs baseline: 1.3947x; 1.3947x over previous
//
#include <hip/hip_runtime.h>
#include <hip/hip_bf16.h>
#include <stdint.h>

// Problem constants
#define BATCH   4096
#define CONTENT 200
#define EMBED   128
#define HIDDEN  1024
#define KDIM    (CONTENT*EMBED)   // 25600
#define KSTEPS64 (KDIM/64)        // 400 K-tiles of 64
#define SPLITK  3
#define KCHUNK64 134              // ceil(400/3); chunks 134,134,132; all starts even

typedef __bf16 bf16_t;
typedef __bf16 bf16x8 __attribute__((ext_vector_type(8)));
typedef float  f32x4  __attribute__((ext_vector_type(4)));

// Workspace layout (bytes)
#define WS_EMBT  0ull                      // emb bf16 [50000][128] = 12,800,000 B
#define WS_W1    12800000ull               // w1 bf16 [1024][25600] = 52,428,800 B
#define WS_HP    65228800ull               // 3 x f32 [4096][1024]  = 50,331,648 B
#define HP_STRIDE 4194304ull               // floats per partial buffer

__device__ __forceinline__ void gload_lds16(const void* g, void* l) {
  __builtin_amdgcn_global_load_lds(
      (const __attribute__((address_space(1))) uint32_t*)g,
      (__attribute__((address_space(3))) uint32_t*)l, 16, 0, 0);
}

// ---------------- Kernel 1: cast emb table f32 -> bf16, zero row 0 ----------------
__global__ __launch_bounds__(256) void k_cast_emb(const float* __restrict__ emb,
                                                  bf16_t* __restrict__ o) {
  const int NU = 50000 * EMBED / 8;   // 800,000 units of 8
  int stride = gridDim.x * 256;
  for (int u = blockIdx.x * 256 + threadIdx.x; u < NU; u += stride) {
    const float4* s = (const float4*)(emb + (size_t)u * 8);
    float4 f0 = s[0], f1 = s[1];
    float sc = (u >> 4) == 0 ? 0.0f : 1.0f;  // padding_idx = 0 (16 units per row)
    bf16x8 r;
    r[0]=(bf16_t)(f0.x*sc); r[1]=(bf16_t)(f0.y*sc); r[2]=(bf16_t)(f0.z*sc); r[3]=(bf16_t)(f0.w*sc);
    r[4]=(bf16_t)(f1.x*sc); r[5]=(bf16_t)(f1.y*sc); r[6]=(bf16_t)(f1.z*sc); r[7]=(bf16_t)(f1.w*sc);
    *(bf16x8*)(o + (size_t)u * 8) = r;
  }
}

// ---------------- Kernel 2: cast w1 f32 -> bf16 ----------------
__global__ __launch_bounds__(256) void k_cast_w1(const float* __restrict__ w1,
                                                 bf16_t* __restrict__ o) {
  const long long NU = (long long)HIDDEN * KDIM / 8;  // 3,276,800 units of 8
  long long stride = (long long)gridDim.x * 256;
  for (long long u = (long long)blockIdx.x * 256 + threadIdx.x; u < NU; u += stride) {
    const float4* s = (const float4*)(w1 + u * 8);
    float4 f0 = s[0], f1 = s[1];
    bf16x8 r;
    r[0]=(bf16_t)f0.x; r[1]=(bf16_t)f0.y; r[2]=(bf16_t)f0.z; r[3]=(bf16_t)f0.w;
    r[4]=(bf16_t)f1.x; r[5]=(bf16_t)f1.y; r[6]=(bf16_t)f1.z; r[7]=(bf16_t)f1.w;
    *(bf16x8*)(o + u * 8) = r;
  }
}

// ---------------- Kernel 3: fused gather-GEMM ----------------
// h_part[z][m][n] = sum_k emb_bf16[x[m][k/128]][k%128] * W[n][k] over chunk z.
// 128x128 tile, BK=64 (128B LDS rows), 2-phase, XOR-swizzled LDS (slot ^= row&7),
// A staged by per-lane GATHERED global_load_lds from the 12.8MB bf16 table.
__global__ __launch_bounds__(256) void k_gemm(const int* __restrict__ x,
                                              const bf16_t* __restrict__ embT,
                                              const bf16_t* __restrict__ W,
                                              float* __restrict__ hp) {
  __shared__ char smem[32768];          // A-tile 16KB | B-tile 16KB
  const int tid = threadIdx.x;
  const int w = tid >> 6, l = tid & 63;
  const int m0 = blockIdx.x * 128;
  const int n0 = blockIdx.y * 128;
  const int chunk = blockIdx.z;
  const int ks_begin = chunk * KCHUNK64;            // always even
  int ks_end = ks_begin + KCHUNK64; if (ks_end > KSTEPS64) ks_end = KSTEPS64;

  // --- staging geometry: thread t stages 4 granules of 16B for A and 4 for B.
  // Granule rd: LDS byte = rd*4096 + t*16  -> row = rd*32 + (t>>3), slot = t&7.
  // Swizzle: LDS slot s at row r holds global k-slot (s ^ (r&7));   (r&7)==((t>>3)&7)
  const int rbase = tid >> 3;                       // row low part, rows rd*32 + rbase
  const int sg = (tid & 7) ^ (rbase & 7);           // pre-swizzled global k-slot
  const char* embB = (const char*)embT;
  const char* Wb = (const char*)W;
  char* dstA0 = smem + w * 1024;                    // wave-uniform; HW adds lane*16
  char* dstB0 = smem + 16384 + w * 1024;

  // B source addresses (advance by 128B per K-tile)
  const char* bsrc[4];
  #pragma unroll
  for (int rd = 0; rd < 4; ++rd)
    bsrc[rd] = Wb + (size_t)(n0 + rd * 32 + rbase) * (KDIM * 2)
                  + (size_t)ks_begin * 128 + sg * 16;

  // x-index prefetch: token c = ks>>1; per-thread rows are fixed.
  int c = ks_begin >> 1;
  int xv[4], xvn[4];
  #pragma unroll
  for (int rd = 0; rd < 4; ++rd)
    xv[rd] = x[(m0 + rd * 32 + rbase) * CONTENT + c];
  {
    int cn = c + 1; if (cn > CONTENT - 1) cn = CONTENT - 1;
    #pragma unroll
    for (int rd = 0; rd < 4; ++rd)
      xvn[rd] = x[(m0 + rd * 32 + rbase) * CONTENT + cn];
  }

  // --- fragment geometry
  const int wr = w >> 1, wc = w & 1;    // wave's 64x64 sub-tile coords
  const int lane_r = l & 15;
  const int g = l >> 4;                 // k-group 0..3
  const char* AsB = smem;
  const char* BsB = smem + 16384;

  f32x4 acc[4][4];
  #pragma unroll
  for (int i = 0; i < 4; ++i)
    #pragma unroll
    for (int j = 0; j < 4; ++j)
      acc[i][j] = (f32x4){0.f, 0.f, 0.f, 0.f};

  for (int ks = ks_begin; ks < ks_end; ++ks) {
    if ((ks & 1) == 0 && ks > ks_begin) {
      // consume prefetched token indices, prefetch next token
      ++c;
      #pragma unroll
      for (int rd = 0; rd < 4; ++rd) xv[rd] = xvn[rd];
      int cn = c + 1; if (cn > CONTENT - 1) cn = CONTENT - 1;
      #pragma unroll
      for (int rd = 0; rd < 4; ++rd)
        xvn[rd] = x[(m0 + rd * 32 + rbase) * CONTENT + cn];
    }
    // stage A (gathered from emb table) + B
    const int koffA = (ks & 1) << 7;    // byte offset within token row (0 or 128)
    #pragma unroll
    for (int rd = 0; rd < 4; ++rd) {
      gload_lds16(embB + (size_t)xv[rd] * 256 + koffA + sg * 16,
                  dstA0 + rd * 4096);
      gload_lds16(bsrc[rd], dstB0 + rd * 4096);
      bsrc[rd] += 128;
    }
    __syncthreads();                    // drains vmcnt(0) (compiler-inserted)

    #pragma unroll
    for (int kk = 0; kk < 2; ++kk) {
      bf16x8 af[4], bfr[4];
      #pragma unroll
      for (int i = 0; i < 4; ++i) {
        int rowa = wr * 64 + i * 16 + lane_r;
        int rowb = wc * 64 + i * 16 + lane_r;
        int slot = ((kk << 2) | g) ^ (lane_r & 7);
        af[i]  = *(const bf16x8*)(AsB + rowa * 128 + slot * 16);
        bfr[i] = *(const bf16x8*)(BsB + rowb * 128 + slot * 16);
      }
      #pragma unroll
      for (int i = 0; i < 4; ++i)
        #pragma unroll
        for (int j = 0; j < 4; ++j)
          acc[i][j] = __builtin_amdgcn_mfma_f32_16x16x32_bf16(af[i], bfr[j], acc[i][j], 0, 0, 0);
    }
    __syncthreads();
  }

  // Epilogue: C/D layout col = lane&15, row = (lane>>4)*4 + reg  [HW-verified round 0]
  float* hout = hp + (size_t)chunk * HP_STRIDE;
  const int colBase = n0 + wc * 64 + lane_r;
  const int rowBase = m0 + wr * 64 + (l >> 4) * 4;
  #pragma unroll
  for (int i = 0; i < 4; ++i)
    #pragma unroll
    for (int j = 0; j < 4; ++j)
      #pragma unroll
      for (int r = 0; r < 4; ++r)
        hout[(size_t)(rowBase + i * 16 + r) * HIDDEN + colBase + j * 16] = acc[i][j][r];
}

// ---------------- Kernel 4: sum partials + bias + relu + layer2 + softmax ----------------
__global__ __launch_bounds__(256) void k_final(const float* __restrict__ hp,
                                               const float* __restrict__ b1,
                                               const float* __restrict__ w2,
                                               const float* __restrict__ b2,
                                               float* __restrict__ out) {
  const int tid = threadIdx.x;
  const int w = tid >> 6, l = tid & 63;
  const int m = blockIdx.x * 4 + w;     // one wave per batch row
  const float* r0 = hp + (size_t)m * HIDDEN;
  const float* r1 = r0 + HP_STRIDE;
  const float* r2 = r1 + HP_STRIDE;
  float l0 = 0.f, l1 = 0.f;
  #pragma unroll
  for (int t = 0; t < 4; ++t) {
    int j = t * 256 + l * 4;
    float4 p0 = *(const float4*)(r0 + j);
    float4 p1 = *(const float4*)(r1 + j);
    float4 p2 = *(const float4*)(r2 + j);
    float4 bb = *(const float4*)(b1 + j);
    float4 wa = *(const float4*)(w2 + j);
    float4 wb = *(const float4*)(w2 + HIDDEN + j);
    float h;
    h = p0.x + p1.x + p2.x + bb.x; h = fmaxf(h, 0.f); l0 += h * wa.x; l1 += h * wb.x;
    h = p0.y + p1.y + p2.y + bb.y; h = fmaxf(h, 0.f); l0 += h * wa.y; l1 += h * wb.y;
    h = p0.z + p1.z + p2.z + bb.z; h = fmaxf(h, 0.f); l0 += h * wa.z; l1 += h * wb.z;
    h = p0.w + p1.w + p2.w + bb.w; h = fmaxf(h, 0.f); l0 += h * wa.w; l1 += h * wb.w;
  }
  #pragma unroll
  for (int off = 32; off > 0; off >>= 1) {
    l0 += __shfl_xor(l0, off, 64);
    l1 += __shfl_xor(l1, off, 64);
  }
  if (l == 0) {
    float z0 = l0 + b2[0], z1 = l1 + b2[1];
    float mx = fmaxf(z0, z1);
    float e0 = expf(z0 - mx), e1 = expf(z1 - mx);
    float s = 1.f / (e0 + e1);
    out[2 * m]     = e0 * s;
    out[2 * m + 1] = e1 * s;
  }
}

extern "C" void kernel_launch(void* const* d_in, const int* in_sizes, int n_in,
                              void* d_out, int out_size, void* d_ws, size_t ws_size,
                              hipStream_t stream) {
  (void)in_sizes; (void)n_in; (void)out_size; (void)ws_size;
  const int*   x   = (const int*)d_in[0];
  const float* emb = (const float*)d_in[1];
  const float* w1  = (const float*)d_in[2];
  const float* b1  = (const float*)d_in[3];
  const float* w2  = (const float*)d_in[4];
  const float* b2  = (const float*)d_in[5];
  float* out = (float*)d_out;
  char* ws = (char*)d_ws;
  bf16_t* embT = (bf16_t*)(ws + WS_EMBT);
  bf16_t* Wbf  = (bf16_t*)(ws + WS_W1);
  float*  hp   = (float*)(ws + WS_HP);

  hipLaunchKernelGGL(k_cast_emb, dim3(1024), dim3(256), 0, stream, emb, embT);
  hipLaunchKernelGGL(k_cast_w1,  dim3(2048), dim3(256), 0, stream, w1, Wbf);
  hipLaunchKernelGGL(k_gemm,     dim3(BATCH/128, HIDDEN/128, SPLITK), dim3(256), 0, stream,
                     x, embT, Wbf, hp);
  hipLaunchKernelGGL(k_final,    dim3(BATCH/4), dim3(256), 0, stream, hp, b1, w2, b2, out);
}